// Round 5
// baseline (240.541 us; speedup 1.0000x reference)
//
#include <hip/hip_runtime.h>

static constexpr int   H         = 4096;
static constexpr int   MAX_STEPS = 16;
static constexpr float EPS       = 0.01f;

static constexpr int TPB  = 256;        // 4 waves/block, 1 wave per row-dot
static constexpr int NB   = H / 4;      // 1024 blocks (B, C)
static constexpr int NB_A = 2 * NB;     // 2048 blocks (A: ih-half + hh-half)

// ws layout (floats):
//   v0[H] | pre1[H] | ah0[H] | hraw[2][H] | CTRL[2] | CNT[16](int)
// v0   = W_ih[:,1:]@x + b_ih + b_hh            (recurrent-step constant)
// pre1 = v0 + W_ih[:,0]                        (step-0 pre-act constant)
// ah0  = W_hh @ s                              (raw, h1 = tanh(pre1+ah0))
// hraw[p] = raw W_hh@h pre-acts (h_{t+1} = tanh(v0 + hraw))
static constexpr int WS_V0   = 0;
static constexpr int WS_PRE1 = H;
static constexpr int WS_AH0  = 2 * H;
static constexpr int WS_HRAW = 3 * H;
static constexpr int WS_CTRL = 5 * H;   // [0]=halted-at-0 flag, [1]=cum0
static constexpr int WS_CNT  = 5 * H + 2;

__device__ __forceinline__ float wave_reduce(float v) {
    #pragma unroll
    for (int off = 32; off > 0; off >>= 1) v += __shfl_down(v, off);
    return v;
}
__device__ __forceinline__ float sigmoidf(float z) { return 1.f / (1.f + __expf(-z)); }

// aligned 4096-dot: one wave, weights row Wr vs LDS vector hs
__device__ __forceinline__ float dot_row16(const float4* __restrict__ Wr,
                                           const float* __restrict__ hs, int lane) {
    float4 w[16];
    #pragma unroll
    for (int it = 0; it < 16; ++it) w[it] = Wr[it * 64 + lane];
    float acc = 0.f;
    #pragma unroll
    for (int it = 0; it < 16; ++it) {
        float4 hv = ((const float4*)hs)[it * 64 + lane];
        acc = fmaf(w[it].x, hv.x, acc);
        acc = fmaf(w[it].y, hv.y, acc);
        acc = fmaf(w[it].z, hv.z, acc);
        acc = fmaf(w[it].w, hv.w, acc);
    }
    return acc;
}

// ==================== A: 8192 row-dots, one per wave, full occupancy ====================
__global__ void __launch_bounds__(TPB, 8)
kA(const float* __restrict__ x,   const float* __restrict__ s,
   const float* __restrict__ Wih, const float* __restrict__ bih,
   const float* __restrict__ Whh, const float* __restrict__ bhh,
   float* __restrict__ ws)
{
    __shared__ float vs[H];
    const int tid = threadIdx.x, lane = tid & 63, wave = tid >> 6;
    const bool ih = (blockIdx.x < (unsigned)NB);
    const int row = (ih ? blockIdx.x : blockIdx.x - NB) * 4 + wave;

    const float* src = ih ? x : s;
    for (int i = tid; i < H / 4; i += TPB)
        ((float4*)vs)[i] = ((const float4*)src)[i];
    if (blockIdx.x == 0 && tid < 16) ((int*)(ws + WS_CNT))[tid] = 0;  // rare-path barrier counters
    __syncthreads();

    if (ih) {
        // W_ih[row][1:] @ x. Row stride H+1=4097 -> per-row misalignment m;
        // aligned-down float4 base, x-index shifted by m.
        const size_t row_off = (size_t)row * (H + 1);
        const size_t start   = row_off + 1;
        const int    m       = (int)(start & 3);
        const float4* wv = (const float4*)(Wih + (start - m));
        float4 w[16];
        #pragma unroll
        for (int it = 0; it < 16; ++it) w[it] = wv[it * 64 + lane];
        float acc = 0.f;
        {   // it = 0: only lane 0's first m slots fall below the row start
            const int kb = lane * 4 - m;
            if (kb + 0 >= 0) acc = fmaf(w[0].x, vs[kb + 0], acc);
            if (kb + 1 >= 0) acc = fmaf(w[0].y, vs[kb + 1], acc);
            if (kb + 2 >= 0) acc = fmaf(w[0].z, vs[kb + 2], acc);
            if (kb + 3 >= 0) acc = fmaf(w[0].w, vs[kb + 3], acc);
        }
        #pragma unroll
        for (int it = 1; it < 16; ++it) {
            const int kb = it * 256 + lane * 4 - m;
            acc = fmaf(w[it].x, vs[kb + 0], acc);
            acc = fmaf(w[it].y, vs[kb + 1], acc);
            acc = fmaf(w[it].z, vs[kb + 2], acc);
            acc = fmaf(w[it].w, vs[kb + 3], acc);
        }
        if (lane < m)
            acc += Wih[start + 4096 - m + lane] * vs[4096 - m + lane];
        acc = wave_reduce(acc);
        if (lane == 0) {
            const float v0 = acc + bih[row] + bhh[row];
            ws[WS_V0   + row] = v0;
            ws[WS_PRE1 + row] = v0 + Wih[row_off];      // + W_ih[row][0]
        }
    } else {
        float acc = dot_row16((const float4*)(Whh + (size_t)row * H), vs, lane);
        acc = wave_reduce(acc);
        if (lane == 0) ws[WS_AH0 + row] = acc;          // raw W_hh@s
    }
}

// ==================== B: fused h1-stage + internal halt0 decision + step-1/output dot ====================
__global__ void __launch_bounds__(TPB, 4)
kB(const float* __restrict__ Whh,   const float* __restrict__ Wout,
   const float* __restrict__ whalt, const float* __restrict__ bhalt,
   const float* __restrict__ bout,  float* __restrict__ ws,
   float* __restrict__ out)
{
    __shared__ float hs[H];
    __shared__ float red[4];
    const int tid = threadIdx.x, lane = tid & 63, wave = tid >> 6;
    const int row = blockIdx.x * 4 + wave;

    // stage full h1 = tanh(pre1 + ah0) and accumulate the COMPLETE halt dot
    // in identical order in every block -> uniform decision, no round-trip.
    float psum = 0.f;
    for (int i = tid; i < H / 4; i += TPB) {
        float4 p  = ((const float4*)(ws + WS_PRE1))[i];
        float4 a  = ((const float4*)(ws + WS_AH0))[i];
        float4 wl = ((const float4*)whalt)[i];
        float4 h;
        h.x = tanhf(p.x + a.x); h.y = tanhf(p.y + a.y);
        h.z = tanhf(p.z + a.z); h.w = tanhf(p.w + a.w);
        ((float4*)hs)[i] = h;
        psum = fmaf(wl.x, h.x, psum); psum = fmaf(wl.y, h.y, psum);
        psum = fmaf(wl.z, h.z, psum); psum = fmaf(wl.w, h.w, psum);
    }
    psum = wave_reduce(psum);
    if (lane == 0) red[wave] = psum;
    __syncthreads();                                     // also orders hs for the dot
    const float cum0 = sigmoidf(red[0] + red[1] + red[2] + red[3] + bhalt[0]);
    const bool halted0 = (cum0 >= 1.f - EPS);
    if (blockIdx.x == 0 && tid == 0) {
        ws[WS_CTRL]     = halted0 ? 1.f : 0.f;
        ws[WS_CTRL + 1] = cum0;
    }

    const float* W = halted0 ? Wout : Whh;               // uniform select
    float acc = dot_row16((const float4*)(W + (size_t)row * H), hs, lane);
    acc = wave_reduce(acc);
    if (lane == 0) {
        if (halted0) {                                   // N=0: emit outputs now
            out[row]     = acc + bout[row];
            out[H + row] = hs[row];
            if (row == 0) out[2 * H] = 0.f;
        } else {
            ws[WS_HRAW + H + row] = acc;                 // raw pre-act of h2
        }
    }
}

// device-wide barrier, RARE path only (1024 blocks, 4/CU vs capacity 8/CU -> co-resident)
__device__ __forceinline__ void gbarrier(int* cnt) {
    __syncthreads();
    if (threadIdx.x == 0) {
        __threadfence();
        atomicAdd(cnt, 1);
        while (atomicAdd(cnt, 0) < NB) __builtin_amdgcn_s_sleep(8);
        __threadfence();
    }
    __syncthreads();
}

// ==================== C: fused h2-stage + decide; rare steps; final dot ====================
__global__ void __launch_bounds__(TPB, 8)
kC(const float* __restrict__ Whh,   const float* __restrict__ Wout,
   const float* __restrict__ whalt, const float* __restrict__ bhalt,
   const float* __restrict__ bout,  float* __restrict__ ws,
   float* __restrict__ out)
{
    if (ws[WS_CTRL] > 0.5f) return;                      // halted at step 0; B emitted
    __shared__ float hs[H];
    __shared__ float red[4];
    const int tid = threadIdx.x, lane = tid & 63, wave = tid >> 6;
    const int row = blockIdx.x * 4 + wave;
    const float bh = bhalt[0];

    float cum = ws[WS_CTRL + 1];
    int N = MAX_STEPS - 1;
    int cur = 1;                                         // hraw[1] = raw h2 from B
    for (int t = 1; t < MAX_STEPS; ++t) {
        // stage h_{t+1} = tanh(v0 + hraw[cur]); full internal halt total
        float psum = 0.f;
        const float4* v0v = (const float4*)(ws + WS_V0);
        const float4* rv  = (const float4*)(ws + WS_HRAW + cur * H);
        for (int i = tid; i < H / 4; i += TPB) {
            float4 v  = v0v[i];
            float4 r  = rv[i];
            float4 wl = ((const float4*)whalt)[i];
            float4 h;
            h.x = tanhf(v.x + r.x); h.y = tanhf(v.y + r.y);
            h.z = tanhf(v.z + r.z); h.w = tanhf(v.w + r.w);
            ((float4*)hs)[i] = h;
            psum = fmaf(wl.x, h.x, psum); psum = fmaf(wl.y, h.y, psum);
            psum = fmaf(wl.z, h.z, psum); psum = fmaf(wl.w, h.w, psum);
        }
        psum = wave_reduce(psum);
        if (lane == 0) red[wave] = psum;
        __syncthreads();                                 // orders hs + red
        cum += sigmoidf(red[0] + red[1] + red[2] + red[3] + bh);
        if (cum >= 1.f - EPS || t == MAX_STEPS - 1) { N = t; break; }

        // rare: raw h_{t+2} = Whh @ h_{t+1}, then device-wide sync
        float acc = dot_row16((const float4*)(Whh + (size_t)row * H), hs, lane);
        acc = wave_reduce(acc);
        if (lane == 0) ws[WS_HRAW + (cur ^ 1) * H + row] = acc;
        gbarrier(((int*)(ws + WS_CNT)) + t);             // also orders hs/red reuse
        cur ^= 1;
    }

    // final: out = W_out @ h_{N+1} ; s_new = h_{N+1} ; ponder = N
    float acc = dot_row16((const float4*)(Wout + (size_t)row * H), hs, lane);
    acc = wave_reduce(acc);
    if (lane == 0) {
        out[row]     = acc + bout[row];
        out[H + row] = hs[row];
        if (row == 0) out[2 * H] = (float)N;
    }
}

extern "C" void kernel_launch(void* const* d_in, const int* in_sizes, int n_in,
                              void* d_out, int out_size, void* d_ws, size_t ws_size,
                              hipStream_t stream) {
    const float* x     = (const float*)d_in[0];
    const float* s     = (const float*)d_in[1];
    const float* Wih   = (const float*)d_in[2];
    const float* bih   = (const float*)d_in[3];
    const float* Whh   = (const float*)d_in[4];
    const float* bhh   = (const float*)d_in[5];
    const float* whalt = (const float*)d_in[6];
    const float* bhalt = (const float*)d_in[7];
    const float* Wout  = (const float*)d_in[8];
    const float* bout  = (const float*)d_in[9];
    float* out = (float*)d_out;
    float* ws  = (float*)d_ws;

    kA<<<NB_A, TPB, 0, stream>>>(x, s, Wih, bih, Whh, bhh, ws);
    kB<<<NB,   TPB, 0, stream>>>(Whh, Wout, whalt, bhalt, bout, ws, out);
    kC<<<NB,   TPB, 0, stream>>>(Whh, Wout, whalt, bhalt, bout, ws, out);
}